// Round 10
// baseline (228.695 us; speedup 1.0000x reference)
//
#include <hip/hip_runtime.h>

// Problem constants (fixed by the reference).
#define N_NODES 50000
#define N_EDGES 800000
#define X_DIM 128
#define H_DIM 256
#define Y_DIM 128

typedef unsigned int uint32;
typedef unsigned short ushort16;
typedef __attribute__((ext_vector_type(8))) short short8;
typedef __attribute__((ext_vector_type(4))) float floatx4;

// bf16 helpers (round-to-nearest-even)
__device__ inline ushort16 f2bf(float f) {
    uint32 u = __float_as_uint(f);
    return (ushort16)((u + 0x7FFFu + ((u >> 16) & 1u)) >> 16);
}
__device__ inline float bf_lo(uint32 u) { return __uint_as_float(u << 16); }
__device__ inline float bf_hi(uint32 u) { return __uint_as_float(u & 0xFFFF0000u); }

// int8 -> float byte extracts. Plain C form: LLVM AMDGPU pattern-matches
// uitofp(and(lshr(u,8k),255)) to v_cvt_f32_ubyte{0-3} (no builtin needed).
__device__ inline float ub0(uint32 u) { return (float)(u & 0xFFu); }
__device__ inline float ub1(uint32 u) { return (float)((u >> 8) & 0xFFu); }
__device__ inline float ub2(uint32 u) { return (float)((u >> 16) & 0xFFu); }
__device__ inline float ub3(uint32 u) { return (float)(u >> 24); }

// Bucket geometry: 391 buckets of 128 rows; 196 chunks of 4096 edges.
#define BUCKET_SHIFT 7
#define NB 391              // ceil(50000/128)
#define CHUNK 4096
#define NCHUNK 196          // ceil(800000/4096)
#define CAP_B 2560          // LDS capacity per bucket (mean 2046)

#define NORM_BLOCKS 12500   // N_NODES*64/256
#define CONV_BLOCKS 256     // 65536/256

// ---------------------------------------------------------------------------
// Prep (fused): row-normalize x -> int8 rows (q = round(x*127/rowmax)) +
// per-row fp32 scale = rowmax*inv/127 (so scale*q == x-hat to ~0.4%);
// transpose-convert W1,W2 to bf16; per-chunk bucket histograms.
// ---------------------------------------------------------------------------
__global__ __launch_bounds__(256) void prep_kernel(
    const float* __restrict__ x, unsigned short* __restrict__ xq,
    float* __restrict__ scales,
    const float* __restrict__ W1, const float* __restrict__ W2,
    ushort16* __restrict__ W1t, ushort16* __restrict__ W2t,
    const int* __restrict__ rows, int* __restrict__ gpartial) {
    int b = blockIdx.x;
    if (b < NORM_BLOCKS) {
        int row = (b * 256 + threadIdx.x) >> 6;  // exact: 12500*4 = 50000 rows
        int lane = threadIdx.x & 63;
        float2 v = ((const float2*)x)[(size_t)row * 64 + lane];
        float s = v.x + v.y;
        float m = fmaxf(v.x, v.y);
        #pragma unroll
        for (int off = 32; off > 0; off >>= 1) {
            s += __shfl_xor(s, off, 64);
            m = fmaxf(m, __shfl_xor(m, off, 64));
        }
        float inv = 1.0f / (s + 1e-4f);
        float rq = (m > 0.f) ? 127.f / m : 0.f;
        int q0 = (int)(v.x * rq + 0.5f);
        int q1 = (int)(v.y * rq + 0.5f);
        xq[(size_t)row * 64 + lane] = (unsigned short)(q0 | (q1 << 8));
        if (lane == 0) scales[row] = m * inv * (1.f / 127.f);
    } else if (b < NORM_BLOCKS + CONV_BLOCKS) {
        int t = (b - NORM_BLOCKS) * 256 + threadIdx.x;  // 0..65535
        if (t < X_DIM * H_DIM) {
            int n = t >> 7, k = t & 127;           // W1t[n][k] = W1[k][n]
            W1t[t] = f2bf(W1[k * H_DIM + n]);
        } else {
            int u = t - X_DIM * H_DIM;
            int y = u >> 8, k = u & 255;           // W2t[y][k] = W2[k][y]
            W2t[u] = f2bf(W2[k * Y_DIM + y]);
        }
    } else {
        __shared__ int h[NB];
        int j = b - NORM_BLOCKS - CONV_BLOCKS;     // chunk id 0..195
        int t = threadIdx.x;
        for (int i = t; i < NB; i += 256) h[i] = 0;
        __syncthreads();
        int base = j * CHUNK;
        #pragma unroll
        for (int k = 0; k < CHUNK / 256; k++) {
            int e = base + t + k * 256;
            if (e < N_EDGES) atomicAdd(&h[rows[e] >> BUCKET_SHIFT], 1);
        }
        __syncthreads();
        for (int i = t; i < NB; i += 256) gpartial[j * NB + i] = h[i];
    }
}

// ---------------------------------------------------------------------------
// Bucket scan (1 block): totals = sum_j gpartial[j][b]; exclusive scan ->
// bucket_base (392 entries) + bcursor seed; rowptr[N] = E.
// ---------------------------------------------------------------------------
__global__ __launch_bounds__(512) void bucket_scan_kernel(
    const int* __restrict__ gpartial, int* __restrict__ bucket_base,
    int* __restrict__ bcursor, int* __restrict__ rowptr) {
    __shared__ int s[512];
    int t = threadIdx.x;
    int total = 0;
    if (t < NB) {
        #pragma unroll 4
        for (int j = 0; j < NCHUNK; j++) total += gpartial[j * NB + t];
    }
    s[t] = total;
    __syncthreads();
    #pragma unroll
    for (int off = 1; off < 512; off <<= 1) {
        int u = (t >= off) ? s[t - off] : 0;
        __syncthreads();
        s[t] += u;
        __syncthreads();
    }
    if (t < NB) {
        int excl = s[t] - total;
        bucket_base[t] = excl;
        bcursor[t] = excl;
    }
    if (t == 0) { bucket_base[NB] = N_EDGES; rowptr[N_NODES] = N_EDGES; }
}

// ---------------------------------------------------------------------------
// Bucketize: compact each 4096-edge chunk into per-bucket LDS runs (offsets
// from gpartial), reserve global ranges via one atomic per bucket, copy out.
// Edge payload: word0 = col(16) | lrow(7) | bucket(9), word1 = fp32 val.
// ---------------------------------------------------------------------------
__global__ __launch_bounds__(512) void bucketize_kernel(
    const int* __restrict__ rows, const int* __restrict__ cols,
    const float* __restrict__ vals, const int* __restrict__ gpartial,
    int* __restrict__ bcursor, int2* __restrict__ edges) {
    __shared__ int ob[512];            // exclusive chunk-local bucket offsets
    __shared__ int c[NB];              // placement cursors
    __shared__ int g[NB];              // reserved global bases
    __shared__ int2 buf[CHUNK];        // 32 KB
    int t = threadIdx.x;
    int j = blockIdx.x;
    int base = j * CHUNK;
    int M = N_EDGES - base; if (M > CHUNK) M = CHUNK;
    int cnt = (t < NB) ? gpartial[j * NB + t] : 0;
    ob[t] = cnt;
    __syncthreads();
    #pragma unroll
    for (int off = 1; off < 512; off <<= 1) {
        int u = (t >= off) ? ob[t - off] : 0;
        __syncthreads();
        ob[t] += u;
        __syncthreads();
    }
    ob[t] -= cnt;  // exclusive (own slot only)
    if (t < NB) {
        c[t] = 0;
        g[t] = (cnt > 0) ? atomicAdd(&bcursor[t], cnt) : 0;
    }
    __syncthreads();
    #pragma unroll
    for (int k = 0; k < CHUNK / 512; k++) {
        int e = base + t + k * 512;
        if (e < N_EDGES) {
            int r = rows[e];
            int bb = r >> BUCKET_SHIFT;
            int p = ob[bb] + atomicAdd(&c[bb], 1);
            buf[p] = make_int2(cols[e] | ((r & 127) << 16) | (bb << 23),
                               __float_as_int(vals[e]));
        }
    }
    __syncthreads();
    for (int i = t; i < M; i += 512) {
        int2 e = buf[i];
        int bb = (int)((uint32)e.x >> 23);
        edges[g[bb] + (i - ob[bb])] = e;
    }
}

// ---------------------------------------------------------------------------
// Bucket sort: per-bucket LDS counting sort by local row, in place; ALSO
// emits rowptr for its 128 rows. Global-scratch fallback if bucket > CAP_B.
// ---------------------------------------------------------------------------
__global__ __launch_bounds__(256) void bucket_sort_kernel(
    const int* __restrict__ bucket_base, int2* __restrict__ edges,
    int2* __restrict__ scratch, int* __restrict__ rowptr) {
    __shared__ int2 buf[CAP_B];   // 20.5 KB
    __shared__ int2 buf2[CAP_B];  // 20.5 KB
    __shared__ int h[128], o[128], c[128];
    int b = blockIdx.x, t = threadIdx.x;
    int base = bucket_base[b];
    int cnt = bucket_base[b + 1] - base;
    bool fits = (cnt <= CAP_B);
    if (t < 128) h[t] = 0;
    __syncthreads();
    for (int i = t; i < cnt; i += 256) {
        int2 e = edges[base + i];
        if (fits) buf[i] = e; else scratch[base + i] = e;
        atomicAdd(&h[(e.x >> 16) & 127], 1);
    }
    __syncthreads();
    int valh = (t < 128) ? h[t] : 0;
    #pragma unroll
    for (int off = 1; off < 128; off <<= 1) {
        int u = (t >= off && t < 128) ? h[t - off] : 0;
        __syncthreads();
        if (t < 128) h[t] += u;
        __syncthreads();
    }
    if (t < 128) {
        o[t] = h[t] - valh;
        c[t] = 0;
        int i = (b << BUCKET_SHIFT) + t;
        if (i < N_NODES) rowptr[i] = base + h[t] - valh;
    }
    __syncthreads();
    for (int i = t; i < cnt; i += 256) {
        int2 e = fits ? buf[i] : scratch[base + i];
        int lr = (e.x >> 16) & 127;
        int p = o[lr] + atomicAdd(&c[lr], 1);
        if (fits) buf2[p] = e; else edges[base + p] = e;
    }
    __syncthreads();
    if (fits)
        for (int i = t; i < cnt; i += 256) edges[base + i] = buf2[i];
}

// ---------------------------------------------------------------------------
// Quad-row INT8 spmm accumulator (unchanged R8): wave = 4 groups of 16
// lanes; group g processes its own row, lane owns dims g16*8..+7 via uint2
// (8 int8 bytes). Edge value premultiplied by the column's row-scale.
// ---------------------------------------------------------------------------
__device__ __forceinline__ void spmm_row4_q8(const uint2* __restrict__ xq2,
                                             const float* __restrict__ scales,
                                             const int2* __restrict__ edges,
                                             int start, int end, int lane,
                                             float A[8]) {
    const int g16 = lane & 15;    // lane-in-group
    const int bsrc = lane & 48;   // shfl source base for my group
    int cur = start;
    while (__any(cur < end)) {
        int n = end - cur;
        n = n < 0 ? 0 : (n > 16 ? 16 : n);
        int2 ev = make_int2(0, 0);
        float sc = 0.f;
        if (g16 < n) {
            ev = edges[cur + g16];
            sc = scales[ev.x & 0xFFFF];
        }
        int c = ev.x & 0xFFFF;
        float vs = __int_as_float(ev.y) * sc;   // v * row-scale, premerged
        int n0 = __shfl(n, 0, 64), n1 = __shfl(n, 16, 64);
        int n2 = __shfl(n, 32, 64), n3 = __shfl(n, 48, 64);
        int nm = max(max(n0, n1), max(n2, n3));
        int jm = (nm + 7) & ~7;
        for (int j = 0; j < jm; j += 8) {
            uint2 f[8];
            float vv[8];
            #pragma unroll
            for (int u = 0; u < 8; u++) {
                int cc = __shfl(c, bsrc + j + u, 64);
                vv[u] = __shfl(vs, bsrc + j + u, 64);
                f[u] = xq2[(size_t)cc * 16 + g16];
            }
            #pragma unroll
            for (int u = 0; u < 8; u++) {
                A[0] += vv[u] * ub0(f[u].x); A[1] += vv[u] * ub1(f[u].x);
                A[2] += vv[u] * ub2(f[u].x); A[3] += vv[u] * ub3(f[u].x);
                A[4] += vv[u] * ub0(f[u].y); A[5] += vv[u] * ub1(f[u].y);
                A[6] += vv[u] * ub2(f[u].y); A[7] += vv[u] * ub3(f[u].y);
            }
        }
        cur += n;
    }
}

// ---------------------------------------------------------------------------
// Quad-row bf16 spmm accumulator (unchanged R4): second spmm.
// ---------------------------------------------------------------------------
__device__ __forceinline__ void spmm_row4(const uint4* __restrict__ feat4,
                                          const int2* __restrict__ edges,
                                          int start, int end, int lane,
                                          float A[8]) {
    const int g16 = lane & 15;    // lane-in-group
    const int bsrc = lane & 48;   // shfl source base for my group
    int cur = start;
    while (__any(cur < end)) {
        int n = end - cur;
        n = n < 0 ? 0 : (n > 16 ? 16 : n);
        int2 ev = make_int2(0, 0);
        if (g16 < n) ev = edges[cur + g16];
        int c = ev.x & 0xFFFF;
        float v = __int_as_float(ev.y);
        int n0 = __shfl(n, 0, 64), n1 = __shfl(n, 16, 64);
        int n2 = __shfl(n, 32, 64), n3 = __shfl(n, 48, 64);
        int nm = max(max(n0, n1), max(n2, n3));
        int jm = (nm + 7) & ~7;
        for (int j = 0; j < jm; j += 8) {
            uint4 f[8];
            float vv[8];
            #pragma unroll
            for (int u = 0; u < 8; u++) {
                int cc = __shfl(c, bsrc + j + u, 64);
                vv[u] = __shfl(v, bsrc + j + u, 64);
                f[u] = feat4[(size_t)cc * 16 + g16];
            }
            #pragma unroll
            for (int u = 0; u < 8; u++) {
                A[0] += vv[u] * bf_lo(f[u].x); A[1] += vv[u] * bf_hi(f[u].x);
                A[2] += vv[u] * bf_lo(f[u].y); A[3] += vv[u] * bf_hi(f[u].y);
                A[4] += vv[u] * bf_lo(f[u].z); A[5] += vv[u] * bf_hi(f[u].z);
                A[6] += vv[u] * bf_lo(f[u].w); A[7] += vv[u] * bf_hi(f[u].w);
            }
        }
        cur += n;
    }
}

// ---------------------------------------------------------------------------
// Fused SPMM + double GEMM per 64-row tile (512 thr, 8 waves).
// vs R9: launch_bounds back to (512,4) -- R9's (512,8) forced VGPR to 32 and
// re-serialized the gather (dur 45.6 -> 56.4). The gather needs ~56 VGPR for
// its 8-deep batch; 56 <= 64 so the HW can still run 8 waves/SIMD, and the
// halved h_s (34.3 KB LDS) now allows 4 blocks/CU = 32 waves. Both levers
// (waves x in-flight-loads) up simultaneously for the first time.
// ---------------------------------------------------------------------------
__global__ __launch_bounds__(512, 4) void spmm_gemm_fused(
    const uint32* __restrict__ xq, const float* __restrict__ scales,
    const int* __restrict__ rowptr,
    const int2* __restrict__ edges, const ushort16* __restrict__ W1t,
    const ushort16* __restrict__ W2t, const float* __restrict__ b1,
    ushort16* __restrict__ hw) {
    __shared__ ushort16 a_s[64 * 136];  // 17.4 KB (all 64 rows, intact throughout)
    __shared__ ushort16 h_s[32 * 264];  // 16.9 KB (one 32-row half at a time)
    const int tx = threadIdx.x;
    const int wave = tx >> 6, lane = tx & 63;
    const int quad = lane >> 4, l16 = lane & 15;
    const int row0 = blockIdx.x * 64;

    // Phase 0: gather 8 rows per wave (4 at a time, quad-row) into the A-tile
    for (int i = 0; i < 2; i++) {
        int r = wave * 8 + i * 4 + quad;
        int row = row0 + r;
        int s = 0, e = 0;
        if (row < N_NODES) { s = rowptr[row]; e = rowptr[row + 1]; }
        float A[8] = {0.f, 0.f, 0.f, 0.f, 0.f, 0.f, 0.f, 0.f};
        spmm_row4_q8((const uint2*)xq, scales, edges, s, e, lane, A);
        uint4 pk;
        pk.x = (uint32)f2bf(A[0]) | ((uint32)f2bf(A[1]) << 16);
        pk.y = (uint32)f2bf(A[2]) | ((uint32)f2bf(A[3]) << 16);
        pk.z = (uint32)f2bf(A[4]) | ((uint32)f2bf(A[5]) << 16);
        pk.w = (uint32)f2bf(A[6]) | ((uint32)f2bf(A[7]) << 16);
        *(uint4*)&a_s[r * 136 + l16 * 8] = pk;
    }
    __syncthreads();   // a_s ready for all waves

    float bv[2];
    #pragma unroll
    for (int ct = 0; ct < 2; ct++) bv[ct] = b1[wave * 32 + ct * 16 + l16];

    // Two 32-row halves: {phase1 -> h_s -> phase2 -> hw} each.
    #pragma unroll
    for (int hf = 0; hf < 2; hf++) {
        if (hf) __syncthreads();   // all phase-2 reads of half 0 done

        // Phase 1 (half): h = relu(A @ W1 + b1) for rows hf*32..hf*32+31
        short8 bfr1[2][4];  // [ct][kk] -- reloaded per half (L2-hot)
        #pragma unroll
        for (int ct = 0; ct < 2; ct++)
            #pragma unroll
            for (int kk = 0; kk < 4; kk++)
                bfr1[ct][kk] = *(const short8*)
                    &W1t[(wave * 32 + ct * 16 + l16) * 128 + kk * 32 + quad * 8];
        floatx4 acc1[2][2];  // [rs2][ct]
        #pragma unroll
        for (int rs2 = 0; rs2 < 2; rs2++)
            #pragma unroll
            for (int ct = 0; ct < 2; ct++)
                #pragma unroll
                for (int j = 0; j < 4; j++) acc1[rs2][ct][j] = 0.f;
        #pragma unroll
        for (int kk = 0; kk < 4; kk++) {
            #pragma unroll
            for (int rs2 = 0; rs2 < 2; rs2++) {
                short8 af = *(const short8*)
                    &a_s[((hf * 2 + rs2) * 16 + l16) * 136 + kk * 32 + quad * 8];
                #pragma unroll
                for (int ct = 0; ct < 2; ct++)
                    acc1[rs2][ct] = __builtin_amdgcn_mfma_f32_16x16x32_bf16(
                        af, bfr1[ct][kk], acc1[rs2][ct], 0, 0, 0);
            }
        }
        #pragma unroll
        for (int rs2 = 0; rs2 < 2; rs2++)
            #pragma unroll
            for (int ct = 0; ct < 2; ct++)
                #pragma unroll
                for (int reg = 0; reg < 4; reg++) {
                    float v = acc1[rs2][ct][reg] + bv[ct];
                    v = v > 0.f ? v : 0.f;
                    h_s[(rs2 * 16 + quad * 4 + reg) * 264 + wave * 32 + ct * 16 + l16]
                        = f2bf(v);
                }

        // Phase 2 (half): hw = h @ W2 for rows hf*32..hf*32+31
        short8 bfr2[8];  // reloaded per half
        #pragma unroll
        for (int kk = 0; kk < 8; kk++)
            bfr2[kk] = *(const short8*)
                &W2t[(wave * 16 + l16) * 256 + kk * 32 + quad * 8];
        __syncthreads();   // h_s half ready

        floatx4 acc2[2];
        #pragma unroll
        for (int rs2 = 0; rs2 < 2; rs2++)
            #pragma unroll
            for (int j = 0; j < 4; j++) acc2[rs2][j] = 0.f;
        #pragma unroll
        for (int kk = 0; kk < 8; kk++) {
            #pragma unroll
            for (int rs2 = 0; rs2 < 2; rs2++) {
                short8 af = *(const short8*)
                    &h_s[(rs2 * 16 + l16) * 264 + kk * 32 + quad * 8];
                acc2[rs2] = __builtin_amdgcn_mfma_f32_16x16x32_bf16(
                    af, bfr2[kk], acc2[rs2], 0, 0, 0);
            }
        }
        #pragma unroll
        for (int rs2 = 0; rs2 < 2; rs2++)
            #pragma unroll
            for (int reg = 0; reg < 4; reg++) {
                int row = row0 + hf * 32 + rs2 * 16 + quad * 4 + reg;
                if (row < N_NODES)
                    hw[(size_t)row * 128 + wave * 16 + l16] = f2bf(acc2[rs2][reg]);
            }
    }
}

// ---------------------------------------------------------------------------
// Final spmm (unchanged R4): out = A @ hw + b2 (fp32 out). One wave per 4
// rows (quad-row). Grid exact: 3125 blocks x 4 waves x 4 rows = 50000.
// ---------------------------------------------------------------------------
__global__ __launch_bounds__(256, 4) void spmm_out_kernel(
    const uint32* __restrict__ feat, const int* __restrict__ rowptr,
    const int2* __restrict__ edges, const float* __restrict__ bias,
    float* __restrict__ out) {
    int w = (blockIdx.x * blockDim.x + threadIdx.x) >> 6;
    int lane = threadIdx.x & 63;
    int quad = lane >> 4, g16 = lane & 15;
    int row = w * 4 + quad;  // always < N_NODES (exact grid)
    int s = rowptr[row], e = rowptr[row + 1];
    float A[8] = {0.f, 0.f, 0.f, 0.f, 0.f, 0.f, 0.f, 0.f};
    spmm_row4((const uint4*)feat, edges, s, e, lane, A);
    float4 b0 = ((const float4*)bias)[g16 * 2];
    float4 b1 = ((const float4*)bias)[g16 * 2 + 1];
    ((float4*)out)[(size_t)row * 32 + g16 * 2] =
        make_float4(A[0] + b0.x, A[1] + b0.y, A[2] + b0.z, A[3] + b0.w);
    ((float4*)out)[(size_t)row * 32 + g16 * 2 + 1] =
        make_float4(A[4] + b1.x, A[5] + b1.y, A[6] + b1.z, A[7] + b1.w);
}

extern "C" void kernel_launch(void* const* d_in, const int* in_sizes, int n_in,
                              void* d_out, int out_size, void* d_ws, size_t ws_size,
                              hipStream_t stream) {
    const float* x = (const float*)d_in[0];
    const float* adj_vals = (const float*)d_in[1];
    const int* adj_row = (const int*)d_in[2];
    const int* adj_col = (const int*)d_in[3];
    const float* W1 = (const float*)d_in[4];
    const float* b1 = (const float*)d_in[5];
    const float* W2 = (const float*)d_in[6];
    const float* b2 = (const float*)d_in[7];
    float* out = (float*)d_out;

    // Workspace layout (~33 MB):
    char* ws = (char*)d_ws;
    unsigned short* xq = (unsigned short*)(ws + 0);      //  6.4 MB (int8 x-hat)
    float*    scales   = (float*)   (ws + 6400000);      //  200 KB (row scales)
    ushort16* hw       = (ushort16*)(ws + 6600000);      // 12.8 MB (bf16)
    int2*     edges    = (int2*)    (ws + 19400000);     //  6.4 MB
    int2*     scratch  = (int2*)    (ws + 25800000);     //  6.4 MB (fallback only)
    int*      gpartial = (int*)     (ws + 32200000);     //  306 KB
    int*      rowptr   = (int*)     (ws + 32507008);     //  200 KB
    int*      bbase    = (int*)     (ws + 32708000);     //  1.6 KB
    int*      bcursor  = (int*)     (ws + 32710048);     //  1.6 KB
    ushort16* W1t      = (ushort16*)(ws + 32712096);     //   64 KB
    ushort16* W2t      = (ushort16*)(ws + 32777632);     //   64 KB

    // 1. prep: int8 x-hat + scales + transposed bf16 weights + bucket hists
    hipLaunchKernelGGL(prep_kernel, dim3(NORM_BLOCKS + CONV_BLOCKS + NCHUNK),
                       dim3(256), 0, stream, x, xq, scales, W1, W2, W1t, W2t,
                       adj_row, gpartial);

    // 2. bucket bases (scan of 391 totals)
    hipLaunchKernelGGL(bucket_scan_kernel, dim3(1), dim3(512),
                       0, stream, gpartial, bbase, bcursor, rowptr);

    // 3. bucketize (coalesced) + per-bucket sort (emits rowptr)
    hipLaunchKernelGGL(bucketize_kernel, dim3(NCHUNK), dim3(512),
                       0, stream, adj_row, adj_col, adj_vals, gpartial, bcursor, edges);
    hipLaunchKernelGGL(bucket_sort_kernel, dim3(NB), dim3(256),
                       0, stream, bbase, edges, scratch, rowptr);

    // 4. hw = relu((A @ x-hat) @ W1 + b1) @ W2   [fused int8 spmm + MFMA]
    hipLaunchKernelGGL(spmm_gemm_fused, dim3((N_NODES + 63) / 64), dim3(512),
                       0, stream, (const uint32*)xq, scales, rowptr, edges,
                       W1t, W2t, b1, hw);

    // 5. out = A @ hw + b2
    hipLaunchKernelGGL(spmm_out_kernel, dim3(N_NODES / 16), dim3(256),
                       0, stream, (const uint32*)hw, rowptr, edges, b2, out);
}

// Round 12
// 222.020 us; speedup vs baseline: 1.0301x; 1.0301x over previous
//
#include <hip/hip_runtime.h>

// Problem constants (fixed by the reference).
#define N_NODES 50000
#define N_EDGES 800000
#define X_DIM 128
#define H_DIM 256
#define Y_DIM 128

typedef unsigned int uint32;
typedef unsigned short ushort16;
typedef __attribute__((ext_vector_type(8))) short short8;
typedef __attribute__((ext_vector_type(4))) float floatx4;

// bf16 helpers (round-to-nearest-even)
__device__ inline ushort16 f2bf(float f) {
    uint32 u = __float_as_uint(f);
    return (ushort16)((u + 0x7FFFu + ((u >> 16) & 1u)) >> 16);
}
__device__ inline float bf_lo(uint32 u) { return __uint_as_float(u << 16); }
__device__ inline float bf_hi(uint32 u) { return __uint_as_float(u & 0xFFFF0000u); }

// int8 -> float byte extracts. Plain C form: LLVM AMDGPU pattern-matches
// uitofp(and(lshr(u,8k),255)) to v_cvt_f32_ubyte{0-3}.
__device__ inline float ub0(uint32 u) { return (float)(u & 0xFFu); }
__device__ inline float ub1(uint32 u) { return (float)((u >> 8) & 0xFFu); }
__device__ inline float ub2(uint32 u) { return (float)((u >> 16) & 0xFFu); }
__device__ inline float ub3(uint32 u) { return (float)(u >> 24); }

// Bucket geometry: 391 buckets of 128 rows; 196 chunks of 4096 edges.
#define BUCKET_SHIFT 7
#define NB 391              // ceil(50000/128)
#define CHUNK 4096
#define NCHUNK 196          // ceil(800000/4096)
#define CAP_B 2560          // LDS capacity per bucket (mean 2046)

#define NORM_BLOCKS 12500   // N_NODES*64/256
#define CONV_BLOCKS 256     // 65536/256

// ---------------------------------------------------------------------------
// Prep (fused): row-normalize x -> int8 rows (q = round(x*127/rowmax)) +
// per-row fp32 scale = rowmax*inv/127; transpose-convert W1,W2 to bf16;
// per-chunk bucket histograms.
// ---------------------------------------------------------------------------
__global__ __launch_bounds__(256) void prep_kernel(
    const float* __restrict__ x, unsigned short* __restrict__ xq,
    float* __restrict__ scales,
    const float* __restrict__ W1, const float* __restrict__ W2,
    ushort16* __restrict__ W1t, ushort16* __restrict__ W2t,
    const int* __restrict__ rows, int* __restrict__ gpartial) {
    int b = blockIdx.x;
    if (b < NORM_BLOCKS) {
        int row = (b * 256 + threadIdx.x) >> 6;  // exact: 12500*4 = 50000 rows
        int lane = threadIdx.x & 63;
        float2 v = ((const float2*)x)[(size_t)row * 64 + lane];
        float s = v.x + v.y;
        float m = fmaxf(v.x, v.y);
        #pragma unroll
        for (int off = 32; off > 0; off >>= 1) {
            s += __shfl_xor(s, off, 64);
            m = fmaxf(m, __shfl_xor(m, off, 64));
        }
        float inv = 1.0f / (s + 1e-4f);
        float rq = (m > 0.f) ? 127.f / m : 0.f;
        int q0 = (int)(v.x * rq + 0.5f);
        int q1 = (int)(v.y * rq + 0.5f);
        xq[(size_t)row * 64 + lane] = (unsigned short)(q0 | (q1 << 8));
        if (lane == 0) scales[row] = m * inv * (1.f / 127.f);
    } else if (b < NORM_BLOCKS + CONV_BLOCKS) {
        int t = (b - NORM_BLOCKS) * 256 + threadIdx.x;  // 0..65535
        if (t < X_DIM * H_DIM) {
            int n = t >> 7, k = t & 127;           // W1t[n][k] = W1[k][n]
            W1t[t] = f2bf(W1[k * H_DIM + n]);
        } else {
            int u = t - X_DIM * H_DIM;
            int y = u >> 8, k = u & 255;           // W2t[y][k] = W2[k][y]
            W2t[u] = f2bf(W2[k * Y_DIM + y]);
        }
    } else {
        __shared__ int h[NB];
        int j = b - NORM_BLOCKS - CONV_BLOCKS;     // chunk id 0..195
        int t = threadIdx.x;
        for (int i = t; i < NB; i += 256) h[i] = 0;
        __syncthreads();
        int base = j * CHUNK;
        #pragma unroll
        for (int k = 0; k < CHUNK / 256; k++) {
            int e = base + t + k * 256;
            if (e < N_EDGES) atomicAdd(&h[rows[e] >> BUCKET_SHIFT], 1);
        }
        __syncthreads();
        for (int i = t; i < NB; i += 256) gpartial[j * NB + i] = h[i];
    }
}

// ---------------------------------------------------------------------------
// Bucket scan (1 block): totals = sum_j gpartial[j][b]; exclusive scan ->
// bucket_base (392 entries) + bcursor seed; rowptr[N] = E.
// ---------------------------------------------------------------------------
__global__ __launch_bounds__(512) void bucket_scan_kernel(
    const int* __restrict__ gpartial, int* __restrict__ bucket_base,
    int* __restrict__ bcursor, int* __restrict__ rowptr) {
    __shared__ int s[512];
    int t = threadIdx.x;
    int total = 0;
    if (t < NB) {
        #pragma unroll 4
        for (int j = 0; j < NCHUNK; j++) total += gpartial[j * NB + t];
    }
    s[t] = total;
    __syncthreads();
    #pragma unroll
    for (int off = 1; off < 512; off <<= 1) {
        int u = (t >= off) ? s[t - off] : 0;
        __syncthreads();
        s[t] += u;
        __syncthreads();
    }
    if (t < NB) {
        int excl = s[t] - total;
        bucket_base[t] = excl;
        bcursor[t] = excl;
    }
    if (t == 0) { bucket_base[NB] = N_EDGES; rowptr[N_NODES] = N_EDGES; }
}

// ---------------------------------------------------------------------------
// Bucketize: compact each 4096-edge chunk into per-bucket LDS runs (offsets
// from gpartial), reserve global ranges via one atomic per bucket, copy out.
// Edge payload: word0 = col(16) | lrow(7) | bucket(9), word1 = fp32 RAW val
// (both spmm passes share this array -- R11's scale pre-merge corrupted the
// second pass; scale is pipelined inside the q8 gather instead).
// ---------------------------------------------------------------------------
__global__ __launch_bounds__(512) void bucketize_kernel(
    const int* __restrict__ rows, const int* __restrict__ cols,
    const float* __restrict__ vals, const int* __restrict__ gpartial,
    int* __restrict__ bcursor, int2* __restrict__ edges) {
    __shared__ int ob[512];            // exclusive chunk-local bucket offsets
    __shared__ int c[NB];              // placement cursors
    __shared__ int g[NB];              // reserved global bases
    __shared__ int2 buf[CHUNK];        // 32 KB
    int t = threadIdx.x;
    int j = blockIdx.x;
    int base = j * CHUNK;
    int M = N_EDGES - base; if (M > CHUNK) M = CHUNK;
    int cnt = (t < NB) ? gpartial[j * NB + t] : 0;
    ob[t] = cnt;
    __syncthreads();
    #pragma unroll
    for (int off = 1; off < 512; off <<= 1) {
        int u = (t >= off) ? ob[t - off] : 0;
        __syncthreads();
        ob[t] += u;
        __syncthreads();
    }
    ob[t] -= cnt;  // exclusive (own slot only)
    if (t < NB) {
        c[t] = 0;
        g[t] = (cnt > 0) ? atomicAdd(&bcursor[t], cnt) : 0;
    }
    __syncthreads();
    #pragma unroll
    for (int k = 0; k < CHUNK / 512; k++) {
        int e = base + t + k * 512;
        if (e < N_EDGES) {
            int r = rows[e];
            int bb = r >> BUCKET_SHIFT;
            int p = ob[bb] + atomicAdd(&c[bb], 1);
            buf[p] = make_int2(cols[e] | ((r & 127) << 16) | (bb << 23),
                               __float_as_int(vals[e]));
        }
    }
    __syncthreads();
    for (int i = t; i < M; i += 512) {
        int2 e = buf[i];
        int bb = (int)((uint32)e.x >> 23);
        edges[g[bb] + (i - ob[bb])] = e;
    }
}

// ---------------------------------------------------------------------------
// Bucket sort: per-bucket LDS counting sort by local row, in place; ALSO
// emits rowptr for its 128 rows. Global-scratch fallback if bucket > CAP_B.
// ---------------------------------------------------------------------------
__global__ __launch_bounds__(256) void bucket_sort_kernel(
    const int* __restrict__ bucket_base, int2* __restrict__ edges,
    int2* __restrict__ scratch, int* __restrict__ rowptr) {
    __shared__ int2 buf[CAP_B];   // 20.5 KB
    __shared__ int2 buf2[CAP_B];  // 20.5 KB
    __shared__ int h[128], o[128], c[128];
    int b = blockIdx.x, t = threadIdx.x;
    int base = bucket_base[b];
    int cnt = bucket_base[b + 1] - base;
    bool fits = (cnt <= CAP_B);
    if (t < 128) h[t] = 0;
    __syncthreads();
    for (int i = t; i < cnt; i += 256) {
        int2 e = edges[base + i];
        if (fits) buf[i] = e; else scratch[base + i] = e;
        atomicAdd(&h[(e.x >> 16) & 127], 1);
    }
    __syncthreads();
    int valh = (t < 128) ? h[t] : 0;
    #pragma unroll
    for (int off = 1; off < 128; off <<= 1) {
        int u = (t >= off && t < 128) ? h[t - off] : 0;
        __syncthreads();
        if (t < 128) h[t] += u;
        __syncthreads();
    }
    if (t < 128) {
        o[t] = h[t] - valh;
        c[t] = 0;
        int i = (b << BUCKET_SHIFT) + t;
        if (i < N_NODES) rowptr[i] = base + h[t] - valh;
    }
    __syncthreads();
    for (int i = t; i < cnt; i += 256) {
        int2 e = fits ? buf[i] : scratch[base + i];
        int lr = (e.x >> 16) & 127;
        int p = o[lr] + atomicAdd(&c[lr], 1);
        if (fits) buf2[p] = e; else edges[base + p] = e;
    }
    __syncthreads();
    if (fits)
        for (int i = t; i < cnt; i += 256) edges[base + i] = buf2[i];
}

// ---------------------------------------------------------------------------
// Quad-row INT8 spmm accumulator, ROUND-PIPELINED: next round's edge record
// AND its scale load while this round's 16 feature gathers are in flight --
// collapses the serial chain (edge 600cy -> scale 200 -> shuffle -> gather
// 600) to ~(gather). vs = v*scale formed at prefetch time: identical
// arithmetic to R8 (absmax must stay 0.015625). Clamped indices keep the
// prefetch in-bounds; inactive lanes carry vs=0 so padding contributes 0.
// ---------------------------------------------------------------------------
__device__ __forceinline__ void spmm_row4_q8(const uint2* __restrict__ xq2,
                                             const float* __restrict__ scales,
                                             const int2* __restrict__ edges,
                                             int start, int end, int lane,
                                             float A[8]) {
    const int g16 = lane & 15;    // lane-in-group
    const int bsrc = lane & 48;   // shfl source base for my group
    int cur = start;
    int2 ev; float vs;
    {   // prologue: round-0 edge record + scale
        int idx = cur + g16;
        bool ok = idx < end;
        int ci = idx < N_EDGES ? idx : N_EDGES - 1;
        ev = edges[ci];
        float sc = scales[ev.x & 0xFFFF];
        vs = ok ? __int_as_float(ev.y) * sc : 0.f;
    }
    while (__any(cur < end)) {
        int n = end - cur;
        n = n < 0 ? 0 : (n > 16 ? 16 : n);
        // prefetch next round's edge record + scale (hides under gathers)
        int ncur = cur + n;
        int idx = ncur + g16;
        bool ok = idx < end;
        int ci = idx < N_EDGES ? idx : N_EDGES - 1;
        int2 e1 = edges[ci];
        float sc1 = scales[e1.x & 0xFFFF];
        float vs1 = ok ? __int_as_float(e1.y) * sc1 : 0.f;
        // process current round
        int c = ev.x & 0xFFFF;
        int n0 = __shfl(n, 0, 64), n1 = __shfl(n, 16, 64);
        int n2 = __shfl(n, 32, 64), n3 = __shfl(n, 48, 64);
        int nm = max(max(n0, n1), max(n2, n3));
        int jm = (nm + 7) & ~7;
        for (int j = 0; j < jm; j += 8) {
            uint2 f[8];
            float vv[8];
            #pragma unroll
            for (int u = 0; u < 8; u++) {
                int cc = __shfl(c, bsrc + j + u, 64);
                vv[u] = __shfl(vs, bsrc + j + u, 64);
                f[u] = xq2[(size_t)cc * 16 + g16];
            }
            #pragma unroll
            for (int u = 0; u < 8; u++) {
                A[0] += vv[u] * ub0(f[u].x); A[1] += vv[u] * ub1(f[u].x);
                A[2] += vv[u] * ub2(f[u].x); A[3] += vv[u] * ub3(f[u].x);
                A[4] += vv[u] * ub0(f[u].y); A[5] += vv[u] * ub1(f[u].y);
                A[6] += vv[u] * ub2(f[u].y); A[7] += vv[u] * ub3(f[u].y);
            }
        }
        cur = ncur; ev = e1; vs = vs1;
    }
}

// ---------------------------------------------------------------------------
// Quad-row bf16 spmm accumulator, ROUND-PIPELINED: second spmm over bf16 hw.
// Uses the RAW edge value (no scale -- edges.y is the adjacency value).
// ---------------------------------------------------------------------------
__device__ __forceinline__ void spmm_row4(const uint4* __restrict__ feat4,
                                          const int2* __restrict__ edges,
                                          int start, int end, int lane,
                                          float A[8]) {
    const int g16 = lane & 15;    // lane-in-group
    const int bsrc = lane & 48;   // shfl source base for my group
    int cur = start;
    int2 ev; float vs;
    {
        int idx = cur + g16;
        bool ok = idx < end;
        int ci = idx < N_EDGES ? idx : N_EDGES - 1;
        ev = edges[ci];
        vs = ok ? __int_as_float(ev.y) : 0.f;
    }
    while (__any(cur < end)) {
        int n = end - cur;
        n = n < 0 ? 0 : (n > 16 ? 16 : n);
        int ncur = cur + n;
        int idx = ncur + g16;
        bool ok = idx < end;
        int ci = idx < N_EDGES ? idx : N_EDGES - 1;
        int2 e1 = edges[ci];
        float vs1 = ok ? __int_as_float(e1.y) : 0.f;
        int c = ev.x & 0xFFFF;
        int n0 = __shfl(n, 0, 64), n1 = __shfl(n, 16, 64);
        int n2 = __shfl(n, 32, 64), n3 = __shfl(n, 48, 64);
        int nm = max(max(n0, n1), max(n2, n3));
        int jm = (nm + 7) & ~7;
        for (int j = 0; j < jm; j += 8) {
            uint4 f[8];
            float vv[8];
            #pragma unroll
            for (int u = 0; u < 8; u++) {
                int cc = __shfl(c, bsrc + j + u, 64);
                vv[u] = __shfl(vs, bsrc + j + u, 64);
                f[u] = feat4[(size_t)cc * 16 + g16];
            }
            #pragma unroll
            for (int u = 0; u < 8; u++) {
                A[0] += vv[u] * bf_lo(f[u].x); A[1] += vv[u] * bf_hi(f[u].x);
                A[2] += vv[u] * bf_lo(f[u].y); A[3] += vv[u] * bf_hi(f[u].y);
                A[4] += vv[u] * bf_lo(f[u].z); A[5] += vv[u] * bf_hi(f[u].z);
                A[6] += vv[u] * bf_lo(f[u].w); A[7] += vv[u] * bf_hi(f[u].w);
            }
        }
        cur = ncur; ev = e1; vs = vs1;
    }
}

// ---------------------------------------------------------------------------
// Fused SPMM + double GEMM per 64-row tile (512 thr, 8 waves), R8 structure
// (best measured: 45.6 us): full h_s, 51.2 KB LDS, launch_bounds(512,4).
// The 782-block grid is fully co-resident at 3 blocks/CU (R10: extra
// capacity unusable), so the simpler full-width h_s layout stays.
// ---------------------------------------------------------------------------
__global__ __launch_bounds__(512, 4) void spmm_gemm_fused(
    const uint32* __restrict__ xq, const float* __restrict__ scales,
    const int* __restrict__ rowptr,
    const int2* __restrict__ edges, const ushort16* __restrict__ W1t,
    const ushort16* __restrict__ W2t, const float* __restrict__ b1,
    ushort16* __restrict__ hw) {
    __shared__ ushort16 a_s[64 * 136];  // 17.4 KB
    __shared__ ushort16 h_s[64 * 264];  // 33.8 KB
    const int tx = threadIdx.x;
    const int wave = tx >> 6, lane = tx & 63;
    const int quad = lane >> 4, l16 = lane & 15;
    const int row0 = blockIdx.x * 64;

    // Phase 0: gather 8 rows per wave (4 at a time, quad-row) into the A-tile
    for (int i = 0; i < 2; i++) {
        int r = wave * 8 + i * 4 + quad;
        int row = row0 + r;
        int s = 0, e = 0;
        if (row < N_NODES) { s = rowptr[row]; e = rowptr[row + 1]; }
        float A[8] = {0.f, 0.f, 0.f, 0.f, 0.f, 0.f, 0.f, 0.f};
        spmm_row4_q8((const uint2*)xq, scales, edges, s, e, lane, A);
        uint4 pk;
        pk.x = (uint32)f2bf(A[0]) | ((uint32)f2bf(A[1]) << 16);
        pk.y = (uint32)f2bf(A[2]) | ((uint32)f2bf(A[3]) << 16);
        pk.z = (uint32)f2bf(A[4]) | ((uint32)f2bf(A[5]) << 16);
        pk.w = (uint32)f2bf(A[6]) | ((uint32)f2bf(A[7]) << 16);
        *(uint4*)&a_s[r * 136 + l16 * 8] = pk;
    }

    // Preload stage-1 B fragments AFTER the gather (register pressure):
    // wave owns h-cols [wave*32, wave*32+32)
    short8 bfr1[2][4];  // [ct][kk]
    #pragma unroll
    for (int ct = 0; ct < 2; ct++)
        #pragma unroll
        for (int kk = 0; kk < 4; kk++)
            bfr1[ct][kk] = *(const short8*)
                &W1t[(wave * 32 + ct * 16 + l16) * 128 + kk * 32 + quad * 8];
    __syncthreads();

    // Phase 1: h = relu(A @ W1 + b1)
    floatx4 acc1[4][2];  // [rs][ct]
    #pragma unroll
    for (int rs = 0; rs < 4; rs++)
        #pragma unroll
        for (int ct = 0; ct < 2; ct++)
            #pragma unroll
            for (int j = 0; j < 4; j++) acc1[rs][ct][j] = 0.f;
    #pragma unroll
    for (int kk = 0; kk < 4; kk++) {
        #pragma unroll
        for (int rs = 0; rs < 4; rs++) {
            short8 af = *(const short8*)&a_s[(rs * 16 + l16) * 136 + kk * 32 + quad * 8];
            #pragma unroll
            for (int ct = 0; ct < 2; ct++)
                acc1[rs][ct] = __builtin_amdgcn_mfma_f32_16x16x32_bf16(
                    af, bfr1[ct][kk], acc1[rs][ct], 0, 0, 0);
        }
    }
    float bv[2];
    #pragma unroll
    for (int ct = 0; ct < 2; ct++) bv[ct] = b1[wave * 32 + ct * 16 + l16];
    #pragma unroll
    for (int rs = 0; rs < 4; rs++)
        #pragma unroll
        for (int ct = 0; ct < 2; ct++)
            #pragma unroll
            for (int reg = 0; reg < 4; reg++) {
                float v = acc1[rs][ct][reg] + bv[ct];
                v = v > 0.f ? v : 0.f;
                h_s[(rs * 16 + quad * 4 + reg) * 264 + wave * 32 + ct * 16 + l16] = f2bf(v);
            }

    // Preload stage-2 B fragments: wave owns hw-cols [wave*16, wave*16+16)
    short8 bfr2[8];
    #pragma unroll
    for (int kk = 0; kk < 8; kk++)
        bfr2[kk] = *(const short8*)
            &W2t[(wave * 16 + l16) * 256 + kk * 32 + quad * 8];
    __syncthreads();

    // Phase 2: hw = h @ W2
    floatx4 acc2[4];
    #pragma unroll
    for (int rs = 0; rs < 4; rs++)
        #pragma unroll
        for (int j = 0; j < 4; j++) acc2[rs][j] = 0.f;
    #pragma unroll
    for (int kk = 0; kk < 8; kk++) {
        #pragma unroll
        for (int rs = 0; rs < 4; rs++) {
            short8 af = *(const short8*)&h_s[(rs * 16 + l16) * 264 + kk * 32 + quad * 8];
            acc2[rs] = __builtin_amdgcn_mfma_f32_16x16x32_bf16(
                af, bfr2[kk], acc2[rs], 0, 0, 0);
        }
    }
    #pragma unroll
    for (int rs = 0; rs < 4; rs++)
        #pragma unroll
        for (int reg = 0; reg < 4; reg++) {
            int row = row0 + rs * 16 + quad * 4 + reg;
            if (row < N_NODES)
                hw[(size_t)row * 128 + wave * 16 + l16] = f2bf(acc2[rs][reg]);
        }
}

// ---------------------------------------------------------------------------
// Final spmm: out = A @ hw + b2 (fp32 out). One wave per 4 rows (quad-row,
// round-pipelined). Grid exact: 3125 blocks x 4 waves x 4 rows = 50000.
// ---------------------------------------------------------------------------
__global__ __launch_bounds__(256, 4) void spmm_out_kernel(
    const uint32* __restrict__ feat, const int* __restrict__ rowptr,
    const int2* __restrict__ edges, const float* __restrict__ bias,
    float* __restrict__ out) {
    int w = (blockIdx.x * blockDim.x + threadIdx.x) >> 6;
    int lane = threadIdx.x & 63;
    int quad = lane >> 4, g16 = lane & 15;
    int row = w * 4 + quad;  // always < N_NODES (exact grid)
    int s = rowptr[row], e = rowptr[row + 1];
    float A[8] = {0.f, 0.f, 0.f, 0.f, 0.f, 0.f, 0.f, 0.f};
    spmm_row4((const uint4*)feat, edges, s, e, lane, A);
    float4 b0 = ((const float4*)bias)[g16 * 2];
    float4 b1 = ((const float4*)bias)[g16 * 2 + 1];
    ((float4*)out)[(size_t)row * 32 + g16 * 2] =
        make_float4(A[0] + b0.x, A[1] + b0.y, A[2] + b0.z, A[3] + b0.w);
    ((float4*)out)[(size_t)row * 32 + g16 * 2 + 1] =
        make_float4(A[4] + b1.x, A[5] + b1.y, A[6] + b1.z, A[7] + b1.w);
}

extern "C" void kernel_launch(void* const* d_in, const int* in_sizes, int n_in,
                              void* d_out, int out_size, void* d_ws, size_t ws_size,
                              hipStream_t stream) {
    const float* x = (const float*)d_in[0];
    const float* adj_vals = (const float*)d_in[1];
    const int* adj_row = (const int*)d_in[2];
    const int* adj_col = (const int*)d_in[3];
    const float* W1 = (const float*)d_in[4];
    const float* b1 = (const float*)d_in[5];
    const float* W2 = (const float*)d_in[6];
    const float* b2 = (const float*)d_in[7];
    float* out = (float*)d_out;

    // Workspace layout (~33 MB):
    char* ws = (char*)d_ws;
    unsigned short* xq = (unsigned short*)(ws + 0);      //  6.4 MB (int8 x-hat)
    float*    scales   = (float*)   (ws + 6400000);      //  200 KB (row scales)
    ushort16* hw       = (ushort16*)(ws + 6600000);      // 12.8 MB (bf16)
    int2*     edges    = (int2*)    (ws + 19400000);     //  6.4 MB
    int2*     scratch  = (int2*)    (ws + 25800000);     //  6.4 MB (fallback only)
    int*      gpartial = (int*)     (ws + 32200000);     //  306 KB
    int*      rowptr   = (int*)     (ws + 32507008);     //  200 KB
    int*      bbase    = (int*)     (ws + 32708000);     //  1.6 KB
    int*      bcursor  = (int*)     (ws + 32710048);     //  1.6 KB
    ushort16* W1t      = (ushort16*)(ws + 32712096);     //   64 KB
    ushort16* W2t      = (ushort16*)(ws + 32777632);     //   64 KB

    // 1. prep: int8 x-hat + scales + transposed bf16 weights + bucket hists
    hipLaunchKernelGGL(prep_kernel, dim3(NORM_BLOCKS + CONV_BLOCKS + NCHUNK),
                       dim3(256), 0, stream, x, xq, scales, W1, W2, W1t, W2t,
                       adj_row, gpartial);

    // 2. bucket bases (scan of 391 totals)
    hipLaunchKernelGGL(bucket_scan_kernel, dim3(1), dim3(512),
                       0, stream, gpartial, bbase, bcursor, rowptr);

    // 3. bucketize (raw vals) + per-bucket sort (emits rowptr)
    hipLaunchKernelGGL(bucketize_kernel, dim3(NCHUNK), dim3(512),
                       0, stream, adj_row, adj_col, adj_vals, gpartial, bcursor, edges);
    hipLaunchKernelGGL(bucket_sort_kernel, dim3(NB), dim3(256),
                       0, stream, bbase, edges, scratch, rowptr);

    // 4. hw = relu((A @ x-hat) @ W1 + b1) @ W2   [fused int8 spmm + MFMA]
    hipLaunchKernelGGL(spmm_gemm_fused, dim3((N_NODES + 63) / 64), dim3(512),
                       0, stream, (const uint32*)xq, scales, rowptr, edges,
                       W1t, W2t, b1, hw);

    // 5. out = A @ hw + b2
    hipLaunchKernelGGL(spmm_out_kernel, dim3(N_NODES / 16), dim3(256),
                       0, stream, (const uint32*)hw, rowptr, edges, b2, out);
}